// Round 1
// baseline (130.914 us; speedup 1.0000x reference)
//
#include <hip/hip_runtime.h>
#include <math.h>

// DataWindowLoss: mean(sqrt(d^2 + 1e-6)) where d = (7x7 box mean) of
// sum_c(x - y), zero-padded. B=16, C=3, H=W=512, f32 in, scalar f32 out.
//
// Memory-bound: 100.7 MB mandatory read. Single fused kernel:
// channel-sum -> LDS tile -> separable 7-tap box -> Charbonnier -> reduce.

namespace {
constexpr int kB = 16, kC = 3, kH = 512, kW = 512;
constexpr int TH = 64;           // output tile height
constexpr int TW = 64;           // output tile width
constexpr int RH = TH + 6;       // 70 rows incl. 3-halo each side
constexpr int RW = TW + 8;       // 72 cols: 3-halo rounded to float4 alignment
constexpr int RW4 = RW / 4;      // 18 float4 slots per row
constexpr int NTHREADS = 256;
}

__global__ void zero_out_kernel(float* out) { out[0] = 0.0f; }

__global__ __launch_bounds__(NTHREADS, 4)
void charbox_kernel(const float* __restrict__ x, const float* __restrict__ y,
                    float* __restrict__ out) {
  __shared__ float zs[RH][RW];       // channel-summed diff, 70x72 (20160 B)
  __shared__ float hs[RH][TW];       // horizontal 7-tap sums, 70x64 (17920 B)
  __shared__ float red[NTHREADS / 64];

  const int tid = threadIdx.x;
  const int w0 = blockIdx.x * TW;
  const int h0 = blockIdx.y * TH;
  const int b  = blockIdx.z;

  const size_t HW = (size_t)kH * kW;
  const float* xb = x + (size_t)b * kC * HW;
  const float* yb = y + (size_t)b * kC * HW;
  const int cs4 = (int)(HW / 4);     // channel stride in float4s

  // ---- Phase 1: z = sum_c (x - y) into LDS, float4 loads, zero padding.
  // Region: rows h0-3 .. h0+66, cols w0-4 .. w0+67 (aligned superset of halo).
  // W=512 and 4-aligned region start => every float4 fully in or out of image.
  for (int s = tid; s < RH * RW4; s += NTHREADS) {
    const int r  = s / RW4;
    const int j4 = s - r * RW4;
    const int h  = h0 - 3 + r;
    const int wb = w0 - 4 + j4 * 4;
    float4 z = make_float4(0.f, 0.f, 0.f, 0.f);
    if ((unsigned)h < (unsigned)kH && (unsigned)wb < (unsigned)kW) {
      const float4* xp = (const float4*)(xb + (size_t)h * kW + wb);
      const float4* yp = (const float4*)(yb + (size_t)h * kW + wb);
      const float4 x0 = xp[0], x1 = xp[cs4], x2 = xp[2 * cs4];
      const float4 y0 = yp[0], y1 = yp[cs4], y2 = yp[2 * cs4];
      z.x = (x0.x - y0.x) + (x1.x - y1.x) + (x2.x - y2.x);
      z.y = (x0.y - y0.y) + (x1.y - y1.y) + (x2.y - y2.y);
      z.z = (x0.z - y0.z) + (x1.z - y1.z) + (x2.z - y2.z);
      z.w = (x0.w - y0.w) + (x1.w - y1.w) + (x2.w - y2.w);
    }
    *(float4*)&zs[r][j4 * 4] = z;
  }
  __syncthreads();

  // ---- Phase 2: horizontal 7-tap sums. Output col wi maps to zs cols wi+1..wi+7.
  for (int s = tid; s < RH * TW; s += NTHREADS) {
    const int r  = s >> 6;
    const int wi = s & (TW - 1);
    float a = zs[r][wi + 1];
#pragma unroll
    for (int t = 2; t <= 7; ++t) a += zs[r][wi + t];
    hs[r][wi] = a;
  }
  __syncthreads();

  // ---- Phase 3: vertical 7-tap + Charbonnier, per-thread accumulate.
  float acc = 0.f;
  for (int s = tid; s < TH * TW; s += NTHREADS) {
    const int hi = s >> 6;
    const int wi = s & (TW - 1);
    float v = hs[hi][wi];
#pragma unroll
    for (int t = 1; t < 7; ++t) v += hs[hi + t][wi];
    const float d = v * (1.0f / 49.0f);
    acc += sqrtf(fmaf(d, d, 1e-6f));
  }

  // ---- Phase 4: wave shfl reduce -> cross-wave LDS reduce -> one atomic.
#pragma unroll
  for (int off = 32; off > 0; off >>= 1) acc += __shfl_down(acc, off, 64);
  const int lane = tid & 63;
  const int wv   = tid >> 6;
  if (lane == 0) red[wv] = acc;
  __syncthreads();
  if (tid == 0) {
    const float ssum = red[0] + red[1] + red[2] + red[3];
    atomicAdd(out, ssum * (1.0f / ((float)kB * (float)kH * (float)kW)));
  }
}

extern "C" void kernel_launch(void* const* d_in, const int* in_sizes, int n_in,
                              void* d_out, int out_size, void* d_ws, size_t ws_size,
                              hipStream_t stream) {
  const float* x = (const float*)d_in[0];
  const float* y = (const float*)d_in[1];
  float* out = (float*)d_out;

  // d_out is re-poisoned to 0xAA before every launch: zero it on-stream.
  zero_out_kernel<<<1, 1, 0, stream>>>(out);

  dim3 grid(kW / TW, kH / TH, kB);   // 8 x 8 x 16 = 1024 blocks (4/CU)
  charbox_kernel<<<grid, NTHREADS, 0, stream>>>(x, y, out);
}